// Round 4
// baseline (10567.949 us; speedup 1.0000x reference)
//
#include <hip/hip_runtime.h>
#include <math.h>

typedef long long ll;

#define BN 65536LL
#define LOSS_OFF (BN * 1024LL)
#define IDX_OFF  (LOSS_OFF + 1LL)

// ---- workspace layout (float offsets) ----
#define WF_W1 0LL                          // B x 512 scratch
#define WF_RT (WF_W1 + BN * 512LL)         // rec_table 2048 x 1024
#define WF_CN (WF_RT + 2048LL * 1024LL)    // cnorm 2048 (fp32)
#define WF_LP (WF_CN + 2048LL)             // loss partials 2048 doubles (8B aligned)
// total ~143 MB

// =================== generic matmul: Y = fl(fl(A@W^T)+b) [+ fl(resid + .)] ===================
// A: B x K (or concat of two B x 512 when A1 != null, K == 1024)
// W: 512 x K row-major. 512 threads, 32 rows x 512 cols per block, 2x16 per thread.
// fp64 accumulation (accumulation-order class vs np fp32 — harmless), fp32 rounding
// at the exact op boundaries the numpy reference materializes.
__global__ __launch_bounds__(512)
void k_mm(const float* __restrict__ A0, const float* __restrict__ A1, int K,
          const float* __restrict__ W, const float* __restrict__ bias,
          const float* __restrict__ resid, float* __restrict__ Y)
{
  __shared__ float As[32][17];
  __shared__ float Bs[16][516];
  const int tid = threadIdx.x;
  const int tx = tid & 31, ty = tid >> 5;   // ty 0..15
  const ll r0 = (ll)blockIdx.x * 32;

  double acc[2][16];
#pragma unroll
  for (int i = 0; i < 2; ++i)
#pragma unroll
    for (int c = 0; c < 16; ++c) acc[i][c] = 0.0;

  for (int kc = 0; kc < K; kc += 16) {
    if (tid < 128) {
      const int rr = tid >> 2, q = tid & 3;
      const int col = kc + q * 4;
      const float* src;
      if (A1 == nullptr) src = A0 + (r0 + rr) * (ll)K + col;
      else if (col < 512) src = A0 + (r0 + rr) * 512LL + col;
      else src = A1 + (r0 + rr) * 512LL + (col - 512);
      const float4 v = *(const float4*)src;
      As[rr][q*4+0] = v.x; As[rr][q*4+1] = v.y; As[rr][q*4+2] = v.z; As[rr][q*4+3] = v.w;
    }
#pragma unroll
    for (int m = 0; m < 4; ++m) {
      const int l = m * 512 + tid;
      const int c = l >> 2, q = l & 3;
      const float4 v = *(const float4*)(W + (ll)c * K + kc + q * 4);
      Bs[q*4+0][c] = v.x; Bs[q*4+1][c] = v.y; Bs[q*4+2][c] = v.z; Bs[q*4+3][c] = v.w;
    }
    __syncthreads();
#pragma unroll
    for (int j = 0; j < 16; ++j) {
      const double a0 = (double)As[ty*2+0][j];
      const double a1 = (double)As[ty*2+1][j];
      const float* bp = &Bs[j][tx*16];
#pragma unroll
      for (int c = 0; c < 16; ++c) {
        const double bb = (double)bp[c];
        acc[0][c] = fma(a0, bb, acc[0][c]);
        acc[1][c] = fma(a1, bb, acc[1][c]);
      }
    }
    __syncthreads();
  }

  float b32[16];
  {
    const float4 q0 = *(const float4*)(bias + tx*16 + 0);
    const float4 q1 = *(const float4*)(bias + tx*16 + 4);
    const float4 q2 = *(const float4*)(bias + tx*16 + 8);
    const float4 q3 = *(const float4*)(bias + tx*16 + 12);
    b32[0]=q0.x; b32[1]=q0.y; b32[2]=q0.z; b32[3]=q0.w;
    b32[4]=q1.x; b32[5]=q1.y; b32[6]=q1.z; b32[7]=q1.w;
    b32[8]=q2.x; b32[9]=q2.y; b32[10]=q2.z; b32[11]=q2.w;
    b32[12]=q3.x; b32[13]=q3.y; b32[14]=q3.z; b32[15]=q3.w;
  }
#pragma unroll
  for (int i = 0; i < 2; ++i) {
    const int row = ty*2 + i;
    float o[16];
    if (resid) {
      const float* rp = resid + (r0 + row) * 512LL + tx*16;
#pragma unroll
      for (int c = 0; c < 16; ++c) {
        const float mm = (float)acc[i][c];   // fl(matmul)
        const float y1 = mm + b32[c];        // fl(+bias)
        o[c] = rp[c] + y1;                   // fl(resid + .)
      }
    } else {
#pragma unroll
      for (int c = 0; c < 16; ++c) {
        const float mm = (float)acc[i][c];
        o[c] = mm + b32[c];
      }
    }
    float* dst = Y + (r0 + row) * 512LL + tx*16;
    *(float4*)(dst+0)  = make_float4(o[0],o[1],o[2],o[3]);
    *(float4*)(dst+4)  = make_float4(o[4],o[5],o[6],o[7]);
    *(float4*)(dst+8)  = make_float4(o[8],o[9],o[10],o[11]);
    *(float4*)(dst+12) = make_float4(o[12],o[13],o[14],o[15]);
  }
}

// =================== LayerNorm, np-fp32 op-boundary exact (optional relu) ===================
// y = fl(fl(fl(fl(x - m) * rs) * w) + b), m = fl(sum/512), v = fl(sum(fl(fl(x-m)^2))/512),
// rs = fl(1 / fl(sqrt(fl(v + 1e-5)))).   4 rows/block, one 64-lane wave per row.
__global__ __launch_bounds__(256)
void k_ln(const float* __restrict__ X, const float* __restrict__ w,
          const float* __restrict__ b, float* __restrict__ Y, int relu)
{
  const int tid = threadIdx.x;
  const int lane = tid & 63, wid = tid >> 6;
  const ll row = (ll)blockIdx.x * 4 + wid;
  const ll base = row * 512;

  float xv[8];
#pragma unroll
  for (int j = 0; j < 8; ++j) xv[j] = X[base + j*64 + lane];

  double s = 0.0;
#pragma unroll
  for (int j = 0; j < 8; ++j) s += (double)xv[j];
#pragma unroll
  for (int off = 32; off > 0; off >>= 1) s += __shfl_down(s, off, 64);
  s = __shfl(s, 0, 64);
  const float m32 = (float)(s * (1.0 / 512.0));

  float xm[8];
  double s2 = 0.0;
#pragma unroll
  for (int j = 0; j < 8; ++j) {
    xm[j] = xv[j] - m32;              // fp32 op
    const float sq = xm[j] * xm[j];   // fp32 op
    s2 += (double)sq;
  }
#pragma unroll
  for (int off = 32; off > 0; off >>= 1) s2 += __shfl_down(s2, off, 64);
  s2 = __shfl(s2, 0, 64);
  const float v32 = (float)(s2 * (1.0 / 512.0));
  const float a32 = v32 + 1e-5f;                  // fp32 add
  const float sq32 = (float)sqrt((double)a32);    // CR fp32 sqrt
  const float rs32 = (float)(1.0 / (double)sq32); // CR fp32 div

#pragma unroll
  for (int j = 0; j < 8; ++j) {
    float o = ((xm[j] * rs32) * w[j*64 + lane]) + b[j*64 + lane]; // fp32 chain
    if (relu) o = fmaxf(o, 0.f);
    Y[base + j*64 + lane] = o;
  }
}

// =================== pre: rec_table (fp64) + cnorm (np-fp32 rounding) ===================
__global__ __launch_bounds__(256)
void k_pre(const float* __restrict__ cbk, const float* __restrict__ d_w1,
           const float* __restrict__ d_b1, const float* __restrict__ d_w2,
           const float* __restrict__ d_b2,
           float* __restrict__ rect, float* __restrict__ cnorm)
{
  __shared__ float cbs16[16][68];
  __shared__ float pbuf[16][516];
  const int tid = threadIdx.x;
  const int bb = blockIdx.x;

  if (bb < 128) {
    const int e0 = bb * 16;
    {
      const int e = tid >> 4, q = tid & 15;
      const float4 v = *(const float4*)(cbk + (ll)(e0 + e) * 64 + q * 4);
      *(float4*)&cbs16[e][q*4] = v;
    }
    __syncthreads();
    {
      double pa0[16], pa1[16];
#pragma unroll
      for (int e = 0; e < 16; ++e) { pa0[e] = 0.0; pa1[e] = 0.0; }
      const int i0 = tid * 2;
      for (int l = 0; l < 64; l += 4) {
        const float4 w0 = *(const float4*)(d_w1 + (ll)i0 * 64 + l);
        const float4 w1 = *(const float4*)(d_w1 + (ll)(i0 + 1) * 64 + l);
#pragma unroll
        for (int e = 0; e < 16; ++e) {
          const float4 c4 = *(const float4*)&cbs16[e][l];
          pa0[e] = fma((double)w0.x,(double)c4.x, fma((double)w0.y,(double)c4.y,
                   fma((double)w0.z,(double)c4.z, fma((double)w0.w,(double)c4.w, pa0[e]))));
          pa1[e] = fma((double)w1.x,(double)c4.x, fma((double)w1.y,(double)c4.y,
                   fma((double)w1.z,(double)c4.z, fma((double)w1.w,(double)c4.w, pa1[e]))));
        }
      }
      const double db0 = (double)d_b1[i0], db1 = (double)d_b1[i0 + 1];
#pragma unroll
      for (int e = 0; e < 16; ++e) {
        pbuf[e][i0]     = (float)fmax(pa0[e] + db0, 0.0);
        pbuf[e][i0 + 1] = (float)fmax(pa1[e] + db1, 0.0);
      }
    }
    __syncthreads();
    {
      double ra[16][4];
#pragma unroll
      for (int e = 0; e < 16; ++e)
#pragma unroll
        for (int k = 0; k < 4; ++k) ra[e][k] = 0.0;
      const int o4 = tid * 4;
      for (int i4 = 0; i4 < 512; i4 += 4) {
        const float4 w0 = *(const float4*)(d_w2 + (ll)(o4+0) * 512 + i4);
        const float4 w1 = *(const float4*)(d_w2 + (ll)(o4+1) * 512 + i4);
        const float4 w2 = *(const float4*)(d_w2 + (ll)(o4+2) * 512 + i4);
        const float4 w3 = *(const float4*)(d_w2 + (ll)(o4+3) * 512 + i4);
#pragma unroll
        for (int e = 0; e < 16; ++e) {
          const float4 p4 = *(const float4*)&pbuf[e][i4];
          ra[e][0] = fma((double)w0.x,(double)p4.x, fma((double)w0.y,(double)p4.y,
                     fma((double)w0.z,(double)p4.z, fma((double)w0.w,(double)p4.w, ra[e][0]))));
          ra[e][1] = fma((double)w1.x,(double)p4.x, fma((double)w1.y,(double)p4.y,
                     fma((double)w1.z,(double)p4.z, fma((double)w1.w,(double)p4.w, ra[e][1]))));
          ra[e][2] = fma((double)w2.x,(double)p4.x, fma((double)w2.y,(double)p4.y,
                     fma((double)w2.z,(double)p4.z, fma((double)w2.w,(double)p4.w, ra[e][2]))));
          ra[e][3] = fma((double)w3.x,(double)p4.x, fma((double)w3.y,(double)p4.y,
                     fma((double)w3.z,(double)p4.z, fma((double)w3.w,(double)p4.w, ra[e][3]))));
        }
      }
      const float4 db = *(const float4*)(d_b2 + o4);
#pragma unroll
      for (int e = 0; e < 16; ++e) {
        *(float4*)(rect + (ll)(e0 + e) * 1024 + o4) =
          make_float4((float)(ra[e][0]+(double)db.x), (float)(ra[e][1]+(double)db.y),
                      (float)(ra[e][2]+(double)db.z), (float)(ra[e][3]+(double)db.w));
      }
    }
  } else {
    // cnorm[k] = fl(sum(fl(c^2)))
    for (int k = tid; k < 2048; k += 256) {
      double s = 0.0;
      for (int l = 0; l < 64; ++l) {
        const float c = cbk[(ll)k * 64 + l];
        const float q = c * c;           // fp32 square
        s += (double)q;
      }
      cnorm[k] = (float)s;
    }
  }
}

// =================== head: h, fp32 dist, argmin(first), loss, rec gather ===================
__global__ __launch_bounds__(256)
void k_head(const float* __restrict__ rin, const float* __restrict__ e_w2,
            const float* __restrict__ e_b2, const float* __restrict__ cbk,
            const float* __restrict__ cnorm, const float* __restrict__ rect,
            float* __restrict__ dout, double* __restrict__ lossP)
{
  __shared__ float As[32][17];
  __shared__ float Bsh[16][68];
  __shared__ float hbuf[32][68];
  __shared__ float hA[32];
  __shared__ float cbs[128][68];
  __shared__ float cns[128];
  __shared__ float redv[32][33];
  __shared__ int   redi[32][33];
  __shared__ int   idxs[32];
  __shared__ double lred[256];
  const int tid = threadIdx.x;
  const int tx = tid & 31, ty = tid >> 5;
  const ll r0 = (ll)blockIdx.x * 32;

  // phase 1: h = fl(fl(r @ e_w2^T) + e_b2)
  double acc2[4][2];
#pragma unroll
  for (int i = 0; i < 4; ++i) { acc2[i][0] = 0.0; acc2[i][1] = 0.0; }
  for (int kc = 0; kc < 512; kc += 16) {
    if (tid < 128) {
      const int rr = tid >> 2, q = tid & 3;
      const float4 v = *(const float4*)(rin + (r0 + rr) * 512LL + kc + q * 4);
      As[rr][q*4+0] = v.x; As[rr][q*4+1] = v.y; As[rr][q*4+2] = v.z; As[rr][q*4+3] = v.w;
    }
    {
      const int c = tid >> 2, q = tid & 3;
      const float4 v = *(const float4*)(e_w2 + (ll)c * 512 + kc + q * 4);
      Bsh[q*4+0][c] = v.x; Bsh[q*4+1][c] = v.y; Bsh[q*4+2][c] = v.z; Bsh[q*4+3][c] = v.w;
    }
    __syncthreads();
#pragma unroll
    for (int j = 0; j < 16; ++j) {
      const double b0 = (double)Bsh[j][tx*2+0], b1 = (double)Bsh[j][tx*2+1];
      const double a0 = (double)As[ty*4+0][j], a1 = (double)As[ty*4+1][j];
      const double a2 = (double)As[ty*4+2][j], a3 = (double)As[ty*4+3][j];
      acc2[0][0] = fma(a0,b0,acc2[0][0]); acc2[0][1] = fma(a0,b1,acc2[0][1]);
      acc2[1][0] = fma(a1,b0,acc2[1][0]); acc2[1][1] = fma(a1,b1,acc2[1][1]);
      acc2[2][0] = fma(a2,b0,acc2[2][0]); acc2[2][1] = fma(a2,b1,acc2[2][1]);
      acc2[3][0] = fma(a3,b0,acc2[3][0]); acc2[3][1] = fma(a3,b1,acc2[3][1]);
    }
    __syncthreads();
  }
  {
    const float eb0 = e_b2[tx*2+0], eb1 = e_b2[tx*2+1];
#pragma unroll
    for (int i = 0; i < 4; ++i) {
      hbuf[ty*4+i][tx*2+0] = (float)acc2[i][0] + eb0;  // fl(mm)+b, fp32
      hbuf[ty*4+i][tx*2+1] = (float)acc2[i][1] + eb1;
    }
  }
  __syncthreads();

  // phase 1.5: A_row = fl(sum(fl(h^2)))
  if (tid < 32) {
    double s = 0.0;
    for (int l = 0; l < 64; ++l) {
      const float hh = hbuf[tid][l];
      const float q = hh * hh;          // fp32 square
      s += (double)q;
    }
    hA[tid] = (float)s;
  }
  __syncthreads();

  // phase 2: dist = fl(fl(A + cn) - 2*fl(h.c)); argmin, first-index ties
  float bestv[4]; int besti[4];
#pragma unroll
  for (int i = 0; i < 4; ++i) { bestv[i] = 3.4e38f; besti[i] = 0; }
  for (int c0 = 0; c0 < 2048; c0 += 128) {
#pragma unroll
    for (int m = 0; m < 8; ++m) {
      const int l = m * 256 + tid;
      const int kk = l >> 4, q = l & 15;
      const float4 v = *(const float4*)(cbk + (ll)(c0 + kk) * 64 + q * 4);
      *(float4*)&cbs[kk][q*4] = v;
    }
    if (tid < 128) cns[tid] = cnorm[c0 + tid];
    __syncthreads();
    double dacc[4][4];
#pragma unroll
    for (int i = 0; i < 4; ++i)
#pragma unroll
      for (int j2 = 0; j2 < 4; ++j2) dacc[i][j2] = 0.0;
#pragma unroll
    for (int l = 0; l < 64; l += 4) {
      float4 ha[4], cv[4];
#pragma unroll
      for (int i = 0; i < 4; ++i) ha[i] = *(const float4*)&hbuf[ty*4+i][l];
#pragma unroll
      for (int j2 = 0; j2 < 4; ++j2) cv[j2] = *(const float4*)&cbs[tx*4+j2][l];
#pragma unroll
      for (int i = 0; i < 4; ++i)
#pragma unroll
        for (int j2 = 0; j2 < 4; ++j2) {
          dacc[i][j2] = fma((double)ha[i].x, (double)cv[j2].x, dacc[i][j2]);
          dacc[i][j2] = fma((double)ha[i].y, (double)cv[j2].y, dacc[i][j2]);
          dacc[i][j2] = fma((double)ha[i].z, (double)cv[j2].z, dacc[i][j2]);
          dacc[i][j2] = fma((double)ha[i].w, (double)cv[j2].w, dacc[i][j2]);
        }
    }
#pragma unroll
    for (int i = 0; i < 4; ++i)
#pragma unroll
      for (int j2 = 0; j2 < 4; ++j2) {
        const float C32 = (float)dacc[i][j2];      // fl(h@c.T)
        const float D = 2.0f * C32;                // exact x2
        const float E = hA[ty*4+i] + cns[tx*4+j2]; // fl(A + cn)
        const float dist = E - D;                  // fl(E - D)
        const int kg = c0 + tx*4 + j2;
        if (dist < bestv[i]) { bestv[i] = dist; besti[i] = kg; }  // ascending kg: first-min
      }
    __syncthreads();
  }
#pragma unroll
  for (int i = 0; i < 4; ++i) { redv[ty*4+i][tx] = bestv[i]; redi[ty*4+i][tx] = besti[i]; }
  __syncthreads();
  if (tid < 32) {
    float bv = redv[tid][0]; int bi = redi[tid][0];
    for (int x = 1; x < 32; ++x) {
      const float v = redv[tid][x]; const int ii = redi[tid][x];
      if (v < bv || (v == bv && ii < bi)) { bv = v; bi = ii; }
    }
    idxs[tid] = bi;
    dout[IDX_OFF + r0 + tid] = (float)bi;
  }
  __syncthreads();

  // phase 3: loss partials, fl per-element ops, fp64 sum
  {
    const int r = tid >> 3, sl = tid & 7;
    const float* cq = cbk + (ll)idxs[r] * 64 + sl * 8;
    double s = 0.0;
#pragma unroll
    for (int e = 0; e < 8; ++e) {
      const float dx = cq[e] - hbuf[r][sl*8 + e];  // fp32 sub
      const float sq = dx * dx;                    // fp32 square
      s += (double)sq;
    }
    lred[tid] = s;
  }
  __syncthreads();
  for (int off = 128; off > 0; off >>= 1) {
    if (tid < off) lred[tid] += lred[tid + off];
    __syncthreads();
  }
  if (tid == 0) lossP[blockIdx.x] = lred[0];

  // phase 4: rec = rec_table[idx]
  for (int m = 0; m < 32; ++m) {
    const float4 v = *(const float4*)(rect + (ll)idxs[m] * 1024 + tid * 4);
    *(float4*)(dout + (r0 + m) * 1024 + tid * 4) = v;
  }
}

// =================== loss reduce: fl(1.25 * fl(S / (B*L))) ===================
__global__ __launch_bounds__(256)
void k_loss(const double* __restrict__ lossP, float* __restrict__ dout)
{
  __shared__ double red[256];
  const int tid = threadIdx.x;
  double s = 0.0;
  for (int i = tid; i < 2048; i += 256) s += lossP[i];
  red[tid] = s;
  __syncthreads();
  for (int off = 128; off > 0; off >>= 1) {
    if (tid < off) red[tid] += red[tid + off];
    __syncthreads();
  }
  if (tid == 0) {
    const float m1 = (float)(red[0] * (1.0 / 4194304.0)); // fl(mean), /2^22 exact scale
    dout[LOSS_OFF] = m1 + 0.25f * m1;                     // fl(m1 + exact 0.25*m1)
  }
}

// =================== launch ===================
extern "C" void kernel_launch(void* const* d_in, const int* in_sizes, int n_in,
                              void* d_out, int out_size, void* d_ws, size_t ws_size,
                              hipStream_t stream)
{
  (void)in_sizes; (void)n_in; (void)out_size; (void)ws_size;
  const float* df    = (const float*)d_in[0];
  const float* tf    = (const float*)d_in[1];
  const float* dp_w  = (const float*)d_in[2];
  const float* dp_b  = (const float*)d_in[3];
  const float* tp_w  = (const float*)d_in[4];
  const float* tp_b  = (const float*)d_in[5];
  const float* in_w  = (const float*)d_in[6];
  const float* in_b  = (const float*)d_in[7];
  const float* out_w = (const float*)d_in[8];
  const float* out_b = (const float*)d_in[9];
  const float* n1w   = (const float*)d_in[10];
  const float* n1b   = (const float*)d_in[11];
  const float* n2w   = (const float*)d_in[12];
  const float* n2b   = (const float*)d_in[13];
  const float* e_w1  = (const float*)d_in[14];
  const float* e_b1  = (const float*)d_in[15];
  const float* e_lnw = (const float*)d_in[16];
  const float* e_lnb = (const float*)d_in[17];
  const float* e_w2  = (const float*)d_in[18];
  const float* e_b2  = (const float*)d_in[19];
  const float* cbk   = (const float*)d_in[20];
  const float* d_w1  = (const float*)d_in[21];
  const float* d_b1  = (const float*)d_in[22];
  const float* d_w2  = (const float*)d_in[23];
  const float* d_b2  = (const float*)d_in[24];
  float* out = (float*)d_out;
  float* ws  = (float*)d_ws;

  float* W1   = ws + WF_W1;
  float* RT   = ws + WF_RT;
  float* CN   = ws + WF_CN;
  double* LP  = (double*)(ws + WF_LP);

  // d_out front as two B x 512 scratch halves (rec overwrites at the end)
  float* OUT0 = out;                 // t, then t2
  float* OUT1 = out + BN * 512LL;    // ln_t1 -> vh_t -> d2

  const float* wv = in_w + 1024LL * 512LL;
  const float* bv = in_b + 1024LL;

  k_pre<<<129, 256, 0, stream>>>(cbk, d_w1, d_b1, d_w2, d_b2, RT, CN);

  // d = fl(fl(df@dp_w^T)+dp_b)
  k_mm<<<2048, 512, 0, stream>>>(df, nullptr, 48, dp_w, dp_b, nullptr, W1);
  // t
  k_mm<<<2048, 512, 0, stream>>>(tf, nullptr, 768, tp_w, tp_b, nullptr, OUT0);
  // ln_t1 = LN(t, n1)
  k_ln<<<16384, 256, 0, stream>>>(OUT0, n1w, n1b, OUT1, 0);
  // vh_t = fl(fl(ln_t1@wv^T)+bv)   (in-place OUT1)
  k_mm<<<2048, 512, 0, stream>>>(OUT1, nullptr, 512, wv, bv, nullptr, OUT1);
  // d2 = fl(d + fl(fl(vh_t@out_w^T)+out_b))   (Y in-place OUT1, resid = d)
  k_mm<<<2048, 512, 0, stream>>>(OUT1, nullptr, 512, out_w, out_b, W1, OUT1);
  // ln_d2 = LN(d, n2)   (in-place W1)
  k_ln<<<16384, 256, 0, stream>>>(W1, n2w, n2b, W1, 0);
  // vh_d   (in-place W1)
  k_mm<<<2048, 512, 0, stream>>>(W1, nullptr, 512, wv, bv, nullptr, W1);
  // t2 = fl(t + fl(fl(vh_d@out_w^T)+out_b))   (resid = t = OUT0, Y = OUT0)
  k_mm<<<2048, 512, 0, stream>>>(W1, nullptr, 512, out_w, out_b, OUT0, OUT0);
  // u = fl(fl([d2|t2]@e_w1^T)+e_b1) -> W1
  k_mm<<<2048, 512, 0, stream>>>(OUT1, OUT0, 1024, e_w1, e_b1, nullptr, W1);
  // r = relu(LN(u, e_ln))   (in-place W1)
  k_ln<<<16384, 256, 0, stream>>>(W1, e_lnw, e_lnb, W1, 1);
  // head: h, dist/argmin, loss partials, rec gather
  k_head<<<2048, 256, 0, stream>>>(W1, e_w2, e_b2, cbk, CN, RT, out, LP);
  k_loss<<<1, 256, 0, stream>>>(LP, out);
}